// Round 19
// baseline (144.254 us; speedup 1.0000x reference)
//
#include <hip/hip_runtime.h>

#define D_MODEL 1024
#define SEQ     2048
#define BATCH   2
#define NHEADS  16
#define DK      64
#define NROWS   (BATCH*SEQ)   // 4096

typedef unsigned short u16;
typedef __bf16 bf16x8 __attribute__((ext_vector_type(8)));
typedef float  f32x4  __attribute__((ext_vector_type(4)));

__device__ __forceinline__ u16 f2bf(float f) {
    union { float f; unsigned u; } v; v.f = f;
    unsigned u = v.u;
    u += 0x7fffu + ((u >> 16) & 1);
    return (u16)(u >> 16);
}
__device__ __forceinline__ float bf2f(u16 h) {
    union { unsigned u; float f; } v; v.u = ((unsigned)h) << 16;
    return v.f;
}
__device__ __forceinline__ unsigned cvtpk_bf16(float lo, float hi) {
    unsigned r;
    asm("v_cvt_pk_bf16_f32 %0, %1, %2" : "=v"(r) : "v"(lo), "v"(hi));
    return r;
}

__device__ __forceinline__ void gload_lds16(const u16* g, u16* l) {
    __builtin_amdgcn_global_load_lds(
        (const __attribute__((address_space(1))) void*)g,
        (__attribute__((address_space(3))) void*)l, 16, 0, 0);
}

// ---------- f32 -> plain bf16 (x + 4 weights) AND RoPE cos/sin table fill ----------
__global__ void cvt_bf16_all(const float* __restrict__ x,
                             const float* __restrict__ w0, const float* __restrict__ w1,
                             const float* __restrict__ w2, const float* __restrict__ w3,
                             u16* __restrict__ xb, u16* __restrict__ wb,
                             float2* __restrict__ tab, const int* __restrict__ pos) {
    int i = blockIdx.x * blockDim.x + threadIdx.x;   // 8192*256 cvt chunks + 65536 tab
    if (i < 2097152) {
        int row = i >> 8;
        int c   = (i & 255) * 4;
        const float* src; u16* dst;
        if (row < 4096) {
            src = x + (size_t)row * 1024;
            dst = xb + (size_t)row * 1024;
        } else {
            int r2 = row - 4096;
            int ws = r2 >> 10;
            int rr = r2 & 1023;
            const float* wsrc = ws == 0 ? w0 : ws == 1 ? w1 : ws == 2 ? w2 : w3;
            src = wsrc + (size_t)rr * 1024;
            dst = wb + ((size_t)ws << 20) + (size_t)rr * 1024;
        }
        float4 v = *(const float4*)(src + c);
        uint2 o;
        o.x = (unsigned)f2bf(v.x) | ((unsigned)f2bf(v.y) << 16);
        o.y = (unsigned)f2bf(v.z) | ((unsigned)f2bf(v.w) << 16);
        *(uint2*)(dst + c) = o;
    } else {
        int e = i - 2097152;           // 0..65535
        int s = e >> 5;                // sequence index
        int k = e & 31;                // pair index within head
        float ang = (float)pos[s] * expf((float)k * -0.28782313662425575f);
        tab[e] = make_float2(cosf(ang), sinf(ang));
    }
}

// ---------- merged QKV GEMM: BK=64, XOR-swizzled staging, coalesced epilogues ----------
// blockIdx.y: [0,8)=Q, [8,16)=K, [16,24)=V (transposed out). All outputs go through a
// 32 KB LDS relayout -> 8x dwordx4 coalesced stores per thread.
__global__ __launch_bounds__(256) void gemm_qkv_p(
    const u16* __restrict__ A, const u16* __restrict__ W,
    u16* __restrict__ Qp, u16* __restrict__ Kp, u16* __restrict__ Vt)
{
    __shared__ __align__(16) u16 SMEM[2 * 128 * 64];   // Ash | Bsh (32 KB)
    u16* Ash = SMEM;
    u16* Bsh = SMEM + 128 * 64;

    const int m0  = blockIdx.x * 128;
    const int sel = blockIdx.y >> 3;
    const int n0  = (blockIdx.y & 7) * 128;
    const u16* B = W + ((size_t)sel << 20);
    const int tid = threadIdx.x;
    const int lane = tid & 63;
    const int w    = tid >> 6;
    const int wr = w >> 1, wc = w & 1;
    const int fr = lane & 15;
    const int fg = lane >> 4;
    const int strow = lane >> 3;
    const int scol  = ((lane & 7) ^ strow) * 8;

    f32x4 acc[4][4];
#pragma unroll
    for (int i = 0; i < 4; ++i)
#pragma unroll
        for (int j = 0; j < 4; ++j) acc[i][j] = (f32x4){0.f, 0.f, 0.f, 0.f};

    for (int k0 = 0; k0 < 1024; k0 += 64) {
        __syncthreads();
#pragma unroll
        for (int s = 0; s < 4; ++s) {
            int st  = 4 * w + s;
            int row = 8 * st + strow;
            gload_lds16(A + (size_t)(m0 + row) * 1024 + k0 + scol, &Ash[8 * st * 64]);
            gload_lds16(B + (size_t)(n0 + row) * 1024 + k0 + scol, &Bsh[8 * st * 64]);
        }
        __syncthreads();
#pragma unroll
        for (int kk = 0; kk < 2; ++kk) {
            bf16x8 ah[4], bh[4];
#pragma unroll
            for (int i = 0; i < 4; ++i) {
                int row = wr * 64 + i * 16 + fr;
                ah[i] = *(const bf16x8*)&Ash[row * 64 + (((kk * 4 + fg) ^ (fr & 7)) * 8)];
            }
#pragma unroll
            for (int j = 0; j < 4; ++j) {
                int row = wc * 64 + j * 16 + fr;
                bh[j] = *(const bf16x8*)&Bsh[row * 64 + (((kk * 4 + fg) ^ (fr & 7)) * 8)];
            }
#pragma unroll
            for (int i = 0; i < 4; ++i)
#pragma unroll
                for (int j = 0; j < 4; ++j)
                    acc[i][j] = __builtin_amdgcn_mfma_f32_16x16x32_bf16(ah[i], bh[j], acc[i][j], 0, 0, 0);
        }
    }

    const int r0 = fg * 4;
    __syncthreads();                      // SMEM reuse: all compute reads done
    u16* CT = SMEM;                       // 128 x 128 u16 = 32 KB, chunk-XOR swizzled
    if (sel == 2) {
        // transposed relayout: CT[col][row]
#pragma unroll
        for (int i = 0; i < 4; ++i)
#pragma unroll
            for (int j = 0; j < 4; ++j) {
                int colr = wc * 64 + j * 16 + fr;
#pragma unroll
                for (int r = 0; r < 4; ++r) {
                    int rowr = wr * 64 + i * 16 + r0 + r;
                    int ch = (rowr >> 3) ^ (colr & 15);
                    CT[colr * 128 + ch * 8 + (rowr & 7)] = f2bf(acc[i][j][r]);
                }
            }
    } else {
        // straight relayout: CT[row][col]
#pragma unroll
        for (int i = 0; i < 4; ++i)
#pragma unroll
            for (int j = 0; j < 4; ++j) {
                int colr = wc * 64 + j * 16 + fr;
#pragma unroll
                for (int r = 0; r < 4; ++r) {
                    int rowr = wr * 64 + i * 16 + r0 + r;
                    int ch = (colr >> 3) ^ (rowr & 15);
                    CT[rowr * 128 + ch * 8 + (colr & 7)] = f2bf(acc[i][j][r]);
                }
            }
    }
    __syncthreads();
    const int orow = tid >> 1;
    const int half = tid & 1;
    u16* dst;
    if (sel == 2)      dst = Vt + (size_t)(n0 + orow) * NROWS + m0 + half * 64;
    else if (sel == 0) dst = Qp + (size_t)(m0 + orow) * 1024 + n0 + half * 64;
    else               dst = Kp + (size_t)(m0 + orow) * 1024 + n0 + half * 64;
#pragma unroll
    for (int cc = 0; cc < 8; ++cc) {
        int ch = (half * 8 + cc) ^ (orow & 15);
        *(uint4*)(dst + cc * 8) = *(const uint4*)&CT[orow * 128 + ch * 8];
    }
}

// ---------- output GEMM: BK=64, XOR-swizzled staging, f32 out ----------
__global__ __launch_bounds__(256) void gemm_out_p(
    const u16* __restrict__ A, const u16* __restrict__ B, float* __restrict__ Cout)
{
    __shared__ __align__(16) u16 SMEM[2 * 128 * 64];
    u16* Ash = SMEM;
    u16* Bsh = SMEM + 128 * 64;

    const int m0 = blockIdx.x * 128;
    const int n0 = blockIdx.y * 128;
    const int tid = threadIdx.x;
    const int lane = tid & 63;
    const int w    = tid >> 6;
    const int wr = w >> 1, wc = w & 1;
    const int fr = lane & 15;
    const int fg = lane >> 4;
    const int strow = lane >> 3;
    const int scol  = ((lane & 7) ^ strow) * 8;

    f32x4 acc[4][4];
#pragma unroll
    for (int i = 0; i < 4; ++i)
#pragma unroll
        for (int j = 0; j < 4; ++j) acc[i][j] = (f32x4){0.f, 0.f, 0.f, 0.f};

    for (int k0 = 0; k0 < 1024; k0 += 64) {
        __syncthreads();
#pragma unroll
        for (int s = 0; s < 4; ++s) {
            int st  = 4 * w + s;
            int row = 8 * st + strow;
            gload_lds16(A + (size_t)(m0 + row) * 1024 + k0 + scol, &Ash[8 * st * 64]);
            gload_lds16(B + (size_t)(n0 + row) * 1024 + k0 + scol, &Bsh[8 * st * 64]);
        }
        __syncthreads();
#pragma unroll
        for (int kk = 0; kk < 2; ++kk) {
            bf16x8 ah[4], bh[4];
#pragma unroll
            for (int i = 0; i < 4; ++i) {
                int row = wr * 64 + i * 16 + fr;
                ah[i] = *(const bf16x8*)&Ash[row * 64 + (((kk * 4 + fg) ^ (fr & 7)) * 8)];
            }
#pragma unroll
            for (int j = 0; j < 4; ++j) {
                int row = wc * 64 + j * 16 + fr;
                bh[j] = *(const bf16x8*)&Bsh[row * 64 + (((kk * 4 + fg) ^ (fr & 7)) * 8)];
            }
#pragma unroll
            for (int i = 0; i < 4; ++i)
#pragma unroll
                for (int j = 0; j < 4; ++j)
                    acc[i][j] = __builtin_amdgcn_mfma_f32_16x16x32_bf16(ah[i], bh[j], acc[i][j], 0, 0, 0);
        }
    }

    const int r0 = fg * 4;
#pragma unroll
    for (int i = 0; i < 4; ++i) {
#pragma unroll
        for (int j = 0; j < 4; ++j) {
            int col = n0 + wc * 64 + j * 16 + fr;
#pragma unroll
            for (int r = 0; r < 4; ++r)
                Cout[(size_t)(m0 + wr * 64 + i * 16 + r0 + r) * 1024 + col] = acc[i][j][r];
        }
    }
}

// ---------- RoPE in place via precomputed table; Q exp2-prescaled ----------
__global__ void rope_table(u16* __restrict__ qk, const float2* __restrict__ tab) {
    int i = blockIdx.x * blockDim.x + threadIdx.x;   // 8192 rows * 512 pairs
    int p = i & 511;
    int n = i >> 9;
    int s = n & 2047;
    int k = p & 31;
    int h = p >> 5;
    size_t base = (size_t)n * 1024 + h * DK + 2 * k;
    unsigned v = *(const unsigned*)&qk[base];
    float x0 = bf2f((u16)(v & 0xffff));
    float x1 = bf2f((u16)(v >> 16));
    float2 cs = tab[s * 32 + k];
    float qs = (n < 4096) ? 0.18033688011112042f : 1.0f;   // 0.125*log2(e) for Q only
    float c = cs.x * qs, sn = cs.y * qs;
    float y0 = x0 * c - x1 * sn;
    float y1 = x1 * c + x0 * sn;
    *(unsigned*)&qk[base] = (unsigned)f2bf(y0) | ((unsigned)f2bf(y1) << 16);
}

// ---------- causal flash attention v10: mid-tile DSW (vmcnt stall hidden under QK^T) ----------
__global__ __launch_bounds__(512, 4) void attn_v10(
    const u16* __restrict__ Qp, const u16* __restrict__ Kp, const u16* __restrict__ Vt,
    u16* __restrict__ Op, float* __restrict__ mlbuf)
{
    const int slot = 39 - (int)blockIdx.x;
    const int h = blockIdx.y, b = blockIdx.z;
    int g, rr;
    if (slot < 4)       { g = 0; rr = slot; }
    else if (slot < 12) { g = 1; rr = slot - 4; }
    else if (slot < 24) { g = 2; rr = slot - 12; }
    else                { g = 3; rr = slot - 24; }
    const int qq  = rr / (g + 1);
    const int qt2 = 4 * g + qq;
    const int c   = rr - qq * (g + 1);

    const int tid  = threadIdx.x;
    const int lane = tid & 63;
    const int w    = tid >> 6;
    const int fr = lane & 15;
    const int fg = lane >> 4;
    const int bS = b * SEQ;
    const int hd = h * DK;
    const int qbase = qt2 * 128 + 16 * w;
    const int ntk = 2 * qt2 + 2;
    const int kt0 = 8 * c;
    const int kt1 = min(8 * c + 8, ntk);

    __shared__ __align__(16) u16 Kl[2][64 * 64];
    __shared__ __align__(16) u16 Vl[2][64 * 64];
    __shared__ __align__(16) u16 Plds[8][16][72];

    const int dsrow  = 8 * w + (lane >> 3);
    const int lincol = (lane & 7) * 8;
    const int dsoff  = dsrow * 64 + (((lane & 7) ^ (lane >> 3)) * 8);
    const int swz    = (fr & 7) * 8;

    const u16* qrow = Qp + (size_t)(bS + qbase + fr) * 1024 + hd;
    bf16x8 qf0 = *(const bf16x8*)(qrow + fg * 8);
    bf16x8 qf1 = *(const bf16x8*)(qrow + 32 + fg * 8);

    f32x4 o[4];
#pragma unroll
    for (int j = 0; j < 4; ++j) o[j] = (f32x4){0.f, 0.f, 0.f, 0.f};
    float mrow = -1e30f, lrow = 0.f;

    uint4 kreg, vreg;
#define LOADR(KT) do { \
    kreg = *(const uint4*)(Kp + (size_t)(bS + (KT) * 64 + dsrow) * 1024 + hd + lincol); \
    vreg = *(const uint4*)(Vt + (size_t)(hd + dsrow) * NROWS + bS + (KT) * 64 + lincol); \
} while (0)
#define DSW(BUF) do { \
    *(uint4*)&Kl[BUF][dsoff] = kreg; \
    *(uint4*)&Vl[BUF][dsoff] = vreg; \
} while (0)

    LOADR(kt0);
    DSW(0);
    if (kt0 + 1 < kt1) LOADR(kt0 + 1);
    __syncthreads();

    int cur = 0;
    for (int kt = kt0; kt < kt1; ++kt) {
        const int k0 = kt * 64;
        const bool part = (k0 <= qbase + 15);
        f32x4 sc4[4];
        if (part) {
            bf16x8 kf[4][2];
#pragma unroll
            for (int t = 0; t < 4; ++t) {
                const u16* kr = &Kl[cur][(16 * t + fr) * 64];
                kf[t][0] = *(const bf16x8*)(kr + ((fg * 8) ^ swz));
                kf[t][1] = *(const bf16x8*)(kr + (((4 + fg) * 8) ^ swz));
            }
            __builtin_amdgcn_s_setprio(1);
#pragma unroll
            for (int t = 0; t < 4; ++t) {
                f32x4 a = (f32x4){0.f, 0.f, 0.f, 0.f};
                a = __builtin_amdgcn_mfma_f32_16x16x32_bf16(kf[t][0], qf0, a, 0, 0, 0);
                a = __builtin_amdgcn_mfma_f32_16x16x32_bf16(kf[t][1], qf1, a, 0, 0, 0);
                sc4[t] = a;
            }
            __builtin_amdgcn_s_setprio(0);
            if (k0 + 63 > qbase) {       // diagonal tile: mask in place
#pragma unroll
                for (int t = 0; t < 4; ++t)
#pragma unroll
                    for (int r = 0; r < 4; ++r)
                        if (k0 + 16 * t + 4 * fg + r > qbase + fr) sc4[t][r] = -1e30f;
            }
        }
        // mid-tile staging: vmcnt wait lands after QK^T; ds_writes overlap softmax VALU
        if (kt + 1 < kt1) {
            DSW(cur ^ 1);
            if (kt + 2 < kt1) LOADR(kt + 2);
        }
        if (part) {
            // common path: direct exp2 against running max, overflow-checked
            float p[4][4];
            float rs = 0.f;
#pragma unroll
            for (int t = 0; t < 4; ++t)
#pragma unroll
                for (int r = 0; r < 4; ++r) {
                    float pv = exp2f(sc4[t][r] - mrow);
                    p[t][r] = pv;
                    rs += pv;
                }
            rs += __shfl_xor(rs, 16);
            rs += __shfl_xor(rs, 32);
            float scf = 1.0f;
            if (!__all(rs < 9.2e18f)) {
                // rare path: first tile or max grew > ~63 log2-units
                float a0 = fmaxf(fmaxf(sc4[0][0], sc4[0][1]), fmaxf(sc4[0][2], sc4[0][3]));
                float a1 = fmaxf(fmaxf(sc4[1][0], sc4[1][1]), fmaxf(sc4[1][2], sc4[1][3]));
                float a2 = fmaxf(fmaxf(sc4[2][0], sc4[2][1]), fmaxf(sc4[2][2], sc4[2][3]));
                float a3 = fmaxf(fmaxf(sc4[3][0], sc4[3][1]), fmaxf(sc4[3][2], sc4[3][3]));
                float mx = fmaxf(fmaxf(a0, a1), fmaxf(a2, a3));
                mx = fmaxf(mx, __shfl_xor(mx, 16));
                mx = fmaxf(mx, __shfl_xor(mx, 32));
                float mnew = fmaxf(mrow, mx);
                scf = exp2f(mrow - mnew);
                float s0 = __shfl(scf, 4 * fg);
                float s1 = __shfl(scf, 4 * fg + 1);
                float s2 = __shfl(scf, 4 * fg + 2);
                float s3 = __shfl(scf, 4 * fg + 3);
#pragma unroll
                for (int j = 0; j < 4; ++j) {
                    o[j][0] *= s0; o[j][1] *= s1; o[j][2] *= s2; o[j][3] *= s3;
                }
                mrow = mnew;
                rs = 0.f;
#pragma unroll
                for (int t = 0; t < 4; ++t)
#pragma unroll
                    for (int r = 0; r < 4; ++r) {
                        float pv = exp2f(sc4[t][r] - mrow);
                        p[t][r] = pv;
                        rs += pv;
                    }
                rs += __shfl_xor(rs, 16);
                rs += __shfl_xor(rs, 32);
            }
            lrow = lrow * scf + rs;
#pragma unroll
            for (int t = 0; t < 4; ++t) {
                uint2 pk;
                pk.x = cvtpk_bf16(p[t][0], p[t][1]);
                pk.y = cvtpk_bf16(p[t][2], p[t][3]);
                *(uint2*)&Plds[w][fr][16 * t + 4 * fg] = pk;
            }
            bf16x8 pf0 = *(const bf16x8*)&Plds[w][fr][fg * 8];
            bf16x8 pf1 = *(const bf16x8*)&Plds[w][fr][32 + fg * 8];
            __builtin_amdgcn_s_setprio(1);
#pragma unroll
            for (int j = 0; j < 4; ++j) {
                const u16* vr = &Vl[cur][(16 * j + fr) * 64];
                bf16x8 v0 = *(const bf16x8*)(vr + ((fg * 8) ^ swz));
                bf16x8 v1 = *(const bf16x8*)(vr + (((4 + fg) * 8) ^ swz));
                o[j] = __builtin_amdgcn_mfma_f32_16x16x32_bf16(pf0, v0, o[j], 0, 0, 0);
                o[j] = __builtin_amdgcn_mfma_f32_16x16x32_bf16(pf1, v1, o[j], 0, 0, 0);
            }
            __builtin_amdgcn_s_setprio(0);
        }
        __syncthreads();
        cur ^= 1;
    }
#undef LOADR
#undef DSW

    const int slotg = (b * NHEADS + h) * 40 + slot;
#pragma unroll
    for (int r = 0; r < 4; ++r) {
        int rrel = 16 * w + 4 * fg + r;
#pragma unroll
        for (int j = 0; j < 4; ++j)
            Op[((size_t)slotg * 128 + rrel) * 64 + 16 * j + fr] = f2bf(o[j][r]);
    }
    if (fg == 0) {
        float* pp = mlbuf + ((size_t)slotg * 128 + 16 * w + fr) * 2;
        pp[0] = mrow;
        pp[1] = lrow;
    }
}

// ---------- combine up-to-4 split-K partials -> Mb (log2-domain weights) ----------
__global__ void attn_combine3(const u16* __restrict__ Op, const float* __restrict__ mlbuf,
                              u16* __restrict__ Mb) {
    int i = blockIdx.x * blockDim.x + threadIdx.x;
    int row = i >> 7;
    int c8  = (i & 127) * 8;
    int h   = c8 >> 6;
    int s   = row & 2047;
    int b   = row >> 11;
    int qt2 = s >> 7;
    int g   = qt2 >> 2;
    int nch = g + 1;
    int slot0 = (b * NHEADS + h) * 40 + 2 * g * (g + 1) + (qt2 & 3) * (g + 1);
    int rrel = s & 127, crel = c8 & 63;

    float mv[4], lv[4];
    float m = -1e30f;
    for (int k = 0; k < nch; ++k) {
        const float* pp = mlbuf + ((size_t)(slot0 + k) * 128 + rrel) * 2;
        mv[k] = pp[0]; lv[k] = pp[1];
        m = fmaxf(m, mv[k]);
    }
    float L = 0.f;
    for (int k = 0; k < nch; ++k) {
        mv[k] = exp2f(mv[k] - m);
        L += lv[k] * mv[k];
    }
    float acc[8];
#pragma unroll
    for (int jj = 0; jj < 8; ++jj) acc[jj] = 0.f;
    for (int k = 0; k < nch; ++k) {
        float wgt = mv[k];
        uint4 u = *(const uint4*)(Op + ((size_t)(slot0 + k) * 128 + rrel) * 64 + crel);
        const unsigned* wrd = (const unsigned*)&u;
#pragma unroll
        for (int kk = 0; kk < 4; ++kk) {
            acc[2 * kk]     += wgt * bf2f((u16)(wrd[kk] & 0xffff));
            acc[2 * kk + 1] += wgt * bf2f((u16)(wrd[kk] >> 16));
        }
    }
    float inv = 1.0f / L;
    unsigned ou[4];
#pragma unroll
    for (int kk = 0; kk < 4; ++kk)
        ou[kk] = (unsigned)f2bf(acc[2 * kk] * inv) | ((unsigned)f2bf(acc[2 * kk + 1] * inv) << 16);
    *(uint4*)(Mb + (size_t)row * 1024 + c8) = *(uint4*)ou;
}

extern "C" void kernel_launch(void* const* d_in, const int* in_sizes, int n_in,
                              void* d_out, int out_size, void* d_ws, size_t ws_size,
                              hipStream_t stream) {
    const float* x   = (const float*)d_in[0];
    const int*   pos = (const int*)d_in[1];
    const float* wq  = (const float*)d_in[2];
    const float* wk  = (const float*)d_in[3];
    const float* wv  = (const float*)d_in[4];
    const float* wo  = (const float*)d_in[5];
    float* out = (float*)d_out;

    char* ws = (char*)d_ws;
    u16* xb  = (u16*)(ws);                    //  8 MB plain [4096][1024]; dead after QKV
    u16* wb  = (u16*)(ws + (24ull << 20));    //  8 MB: wq|wk|wv|wo plain, 2 MB each
    u16* wob = wb + 3 * (1 << 20);            //  [30,32) — survives to the end
    u16* Qp  = (u16*)(ws + (32ull << 20));    //  8 MB plain [4096][1024]
    u16* Kp  = (u16*)(ws + (40ull << 20));    //  8 MB plain
    u16* Vt  = (u16*)(ws + (48ull << 20));    //  8 MB plain transposed [1024][4096]
    u16* Mb  = (u16*)(ws + (56ull << 20));    //  8 MB plain [4096][1024]
    u16* Op  = (u16*)(ws);                    // 21 MB partials (reuses dead xb + gap)
    float* mlbuf = (float*)(ws + (21ull << 20));  // 1.3 MB [21, 22.3)
    float2* tab  = (float2*)(ws + (23ull << 20)); // 512 KB [23, 23.5) — RoPE table

    // 1) convert x + 4 weights to bf16 AND fill RoPE cos/sin table (one launch)
    cvt_bf16_all<<<8448, 256, 0, stream>>>(x, wq, wk, wv, wo, xb, wb, tab, pos);

    // 2) merged QKV projection (BK=64, swizzle, all-coalesced epilogues)
    gemm_qkv_p<<<dim3(NROWS / 128, 24), 256, 0, stream>>>(xb, wb, Qp, Kp, Vt);

    // 3) RoPE in place via table (Q exp2-prescaled)
    rope_table<<<16384, 256, 0, stream>>>(Qp, tab);

    // 4) causal flash attention v10 (mid-tile DSW) + combine
    attn_v10<<<dim3(40, NHEADS, BATCH), 512, 0, stream>>>(Qp, Kp, Vt, Op, mlbuf);
    attn_combine3<<<2048, 256, 0, stream>>>(Op, mlbuf, Mb);

    // 5) output projection (BK=64, swizzled staging, f32 out)
    gemm_out_p<<<dim3(NROWS / 128, 8), 256, 0, stream>>>(Mb, wob, out);
}

// Round 20
// 141.062 us; speedup vs baseline: 1.0226x; 1.0226x over previous
//
#include <hip/hip_runtime.h>

#define D_MODEL 1024
#define SEQ     2048
#define BATCH   2
#define NHEADS  16
#define DK      64
#define NROWS   (BATCH*SEQ)   // 4096

typedef unsigned short u16;
typedef __bf16 bf16x8 __attribute__((ext_vector_type(8)));
typedef float  f32x4  __attribute__((ext_vector_type(4)));

__device__ __forceinline__ u16 f2bf(float f) {
    union { float f; unsigned u; } v; v.f = f;
    unsigned u = v.u;
    u += 0x7fffu + ((u >> 16) & 1);
    return (u16)(u >> 16);
}
__device__ __forceinline__ float bf2f(u16 h) {
    union { unsigned u; float f; } v; v.u = ((unsigned)h) << 16;
    return v.f;
}
__device__ __forceinline__ unsigned cvtpk_bf16(float lo, float hi) {
    unsigned r;
    asm("v_cvt_pk_bf16_f32 %0, %1, %2" : "=v"(r) : "v"(lo), "v"(hi));
    return r;
}

__device__ __forceinline__ void gload_lds16(const u16* g, u16* l) {
    __builtin_amdgcn_global_load_lds(
        (const __attribute__((address_space(1))) void*)g,
        (__attribute__((address_space(3))) void*)l, 16, 0, 0);
}

// ---------- f32 -> plain bf16 (x + 4 weights) AND RoPE cos/sin table fill ----------
__global__ void cvt_bf16_all(const float* __restrict__ x,
                             const float* __restrict__ w0, const float* __restrict__ w1,
                             const float* __restrict__ w2, const float* __restrict__ w3,
                             u16* __restrict__ xb, u16* __restrict__ wb,
                             float2* __restrict__ tab, const int* __restrict__ pos) {
    int i = blockIdx.x * blockDim.x + threadIdx.x;   // 8192*256 cvt chunks + 65536 tab
    if (i < 2097152) {
        int row = i >> 8;
        int c   = (i & 255) * 4;
        const float* src; u16* dst;
        if (row < 4096) {
            src = x + (size_t)row * 1024;
            dst = xb + (size_t)row * 1024;
        } else {
            int r2 = row - 4096;
            int ws = r2 >> 10;
            int rr = r2 & 1023;
            const float* wsrc = ws == 0 ? w0 : ws == 1 ? w1 : ws == 2 ? w2 : w3;
            src = wsrc + (size_t)rr * 1024;
            dst = wb + ((size_t)ws << 20) + (size_t)rr * 1024;
        }
        float4 v = *(const float4*)(src + c);
        uint2 o;
        o.x = (unsigned)f2bf(v.x) | ((unsigned)f2bf(v.y) << 16);
        o.y = (unsigned)f2bf(v.z) | ((unsigned)f2bf(v.w) << 16);
        *(uint2*)(dst + c) = o;
    } else {
        int e = i - 2097152;           // 0..65535
        int s = e >> 5;                // sequence index
        int k = e & 31;                // pair index within head
        float ang = (float)pos[s] * expf((float)k * -0.28782313662425575f);
        tab[e] = make_float2(cosf(ang), sinf(ang));
    }
}

// ---------- merged QKV GEMM: BK=64, XOR-swizzled staging, LDS-transposed V out ----------
// Q/K: direct stores (already ~coalesced). V: LDS relayout -> coalesced dwordx4.
__global__ __launch_bounds__(256) void gemm_qkv_p(
    const u16* __restrict__ A, const u16* __restrict__ W,
    u16* __restrict__ Qp, u16* __restrict__ Kp, u16* __restrict__ Vt)
{
    __shared__ __align__(16) u16 SMEM[2 * 128 * 64];   // Ash | Bsh (32 KB)
    u16* Ash = SMEM;
    u16* Bsh = SMEM + 128 * 64;

    const int m0  = blockIdx.x * 128;
    const int sel = blockIdx.y >> 3;
    const int n0  = (blockIdx.y & 7) * 128;
    const u16* B = W + ((size_t)sel << 20);
    const int tid = threadIdx.x;
    const int lane = tid & 63;
    const int w    = tid >> 6;
    const int wr = w >> 1, wc = w & 1;
    const int fr = lane & 15;
    const int fg = lane >> 4;
    const int strow = lane >> 3;
    const int scol  = ((lane & 7) ^ strow) * 8;

    f32x4 acc[4][4];
#pragma unroll
    for (int i = 0; i < 4; ++i)
#pragma unroll
        for (int j = 0; j < 4; ++j) acc[i][j] = (f32x4){0.f, 0.f, 0.f, 0.f};

    for (int k0 = 0; k0 < 1024; k0 += 64) {
        __syncthreads();
#pragma unroll
        for (int s = 0; s < 4; ++s) {
            int st  = 4 * w + s;
            int row = 8 * st + strow;
            gload_lds16(A + (size_t)(m0 + row) * 1024 + k0 + scol, &Ash[8 * st * 64]);
            gload_lds16(B + (size_t)(n0 + row) * 1024 + k0 + scol, &Bsh[8 * st * 64]);
        }
        __syncthreads();
#pragma unroll
        for (int kk = 0; kk < 2; ++kk) {
            bf16x8 ah[4], bh[4];
#pragma unroll
            for (int i = 0; i < 4; ++i) {
                int row = wr * 64 + i * 16 + fr;
                ah[i] = *(const bf16x8*)&Ash[row * 64 + (((kk * 4 + fg) ^ (fr & 7)) * 8)];
            }
#pragma unroll
            for (int j = 0; j < 4; ++j) {
                int row = wc * 64 + j * 16 + fr;
                bh[j] = *(const bf16x8*)&Bsh[row * 64 + (((kk * 4 + fg) ^ (fr & 7)) * 8)];
            }
#pragma unroll
            for (int i = 0; i < 4; ++i)
#pragma unroll
                for (int j = 0; j < 4; ++j)
                    acc[i][j] = __builtin_amdgcn_mfma_f32_16x16x32_bf16(ah[i], bh[j], acc[i][j], 0, 0, 0);
        }
    }

    const int r0 = fg * 4;
    if (sel == 2) {
        // V: transposed store via LDS relayout (scattered 8KB-stride stores are pathological)
        __syncthreads();
        u16* CT = SMEM;                   // 128 x 128 u16 = 32 KB, chunk-XOR swizzled
#pragma unroll
        for (int i = 0; i < 4; ++i)
#pragma unroll
            for (int j = 0; j < 4; ++j) {
                int colr = wc * 64 + j * 16 + fr;
#pragma unroll
                for (int r = 0; r < 4; ++r) {
                    int rowr = wr * 64 + i * 16 + r0 + r;
                    int ch = (rowr >> 3) ^ (colr & 15);
                    CT[colr * 128 + ch * 8 + (rowr & 7)] = f2bf(acc[i][j][r]);
                }
            }
        __syncthreads();
        const int colr = tid >> 1;
        const int half = tid & 1;
        u16* dst = Vt + (size_t)(n0 + colr) * NROWS + m0 + half * 64;
#pragma unroll
        for (int cc = 0; cc < 8; ++cc) {
            int ch = (half * 8 + cc) ^ (colr & 15);
            *(uint4*)(dst + cc * 8) = *(const uint4*)&CT[colr * 128 + ch * 8];
        }
    } else {
        // Q/K: direct stores (row-major, consecutive fr lanes contiguous — fine as-is)
        u16* Outp = (sel == 0) ? Qp : Kp;
#pragma unroll
        for (int i = 0; i < 4; ++i) {
#pragma unroll
            for (int j = 0; j < 4; ++j) {
                int col = n0 + wc * 64 + j * 16 + fr;
#pragma unroll
                for (int r = 0; r < 4; ++r) {
                    int row = m0 + wr * 64 + i * 16 + r0 + r;
                    Outp[(size_t)row * 1024 + col] = f2bf(acc[i][j][r]);
                }
            }
        }
    }
}

// ---------- output GEMM: BK=64, XOR-swizzled staging, f32 out ----------
__global__ __launch_bounds__(256) void gemm_out_p(
    const u16* __restrict__ A, const u16* __restrict__ B, float* __restrict__ Cout)
{
    __shared__ __align__(16) u16 SMEM[2 * 128 * 64];
    u16* Ash = SMEM;
    u16* Bsh = SMEM + 128 * 64;

    const int m0 = blockIdx.x * 128;
    const int n0 = blockIdx.y * 128;
    const int tid = threadIdx.x;
    const int lane = tid & 63;
    const int w    = tid >> 6;
    const int wr = w >> 1, wc = w & 1;
    const int fr = lane & 15;
    const int fg = lane >> 4;
    const int strow = lane >> 3;
    const int scol  = ((lane & 7) ^ strow) * 8;

    f32x4 acc[4][4];
#pragma unroll
    for (int i = 0; i < 4; ++i)
#pragma unroll
        for (int j = 0; j < 4; ++j) acc[i][j] = (f32x4){0.f, 0.f, 0.f, 0.f};

    for (int k0 = 0; k0 < 1024; k0 += 64) {
        __syncthreads();
#pragma unroll
        for (int s = 0; s < 4; ++s) {
            int st  = 4 * w + s;
            int row = 8 * st + strow;
            gload_lds16(A + (size_t)(m0 + row) * 1024 + k0 + scol, &Ash[8 * st * 64]);
            gload_lds16(B + (size_t)(n0 + row) * 1024 + k0 + scol, &Bsh[8 * st * 64]);
        }
        __syncthreads();
#pragma unroll
        for (int kk = 0; kk < 2; ++kk) {
            bf16x8 ah[4], bh[4];
#pragma unroll
            for (int i = 0; i < 4; ++i) {
                int row = wr * 64 + i * 16 + fr;
                ah[i] = *(const bf16x8*)&Ash[row * 64 + (((kk * 4 + fg) ^ (fr & 7)) * 8)];
            }
#pragma unroll
            for (int j = 0; j < 4; ++j) {
                int row = wc * 64 + j * 16 + fr;
                bh[j] = *(const bf16x8*)&Bsh[row * 64 + (((kk * 4 + fg) ^ (fr & 7)) * 8)];
            }
#pragma unroll
            for (int i = 0; i < 4; ++i)
#pragma unroll
                for (int j = 0; j < 4; ++j)
                    acc[i][j] = __builtin_amdgcn_mfma_f32_16x16x32_bf16(ah[i], bh[j], acc[i][j], 0, 0, 0);
        }
    }

    const int r0 = fg * 4;
#pragma unroll
    for (int i = 0; i < 4; ++i) {
#pragma unroll
        for (int j = 0; j < 4; ++j) {
            int col = n0 + wc * 64 + j * 16 + fr;
#pragma unroll
            for (int r = 0; r < 4; ++r)
                Cout[(size_t)(m0 + wr * 64 + i * 16 + r0 + r) * 1024 + col] = acc[i][j][r];
        }
    }
}

// ---------- RoPE in place via precomputed table; Q exp2-prescaled ----------
__global__ void rope_table(u16* __restrict__ qk, const float2* __restrict__ tab) {
    int i = blockIdx.x * blockDim.x + threadIdx.x;   // 8192 rows * 512 pairs
    int p = i & 511;
    int n = i >> 9;
    int s = n & 2047;
    int k = p & 31;
    int h = p >> 5;
    size_t base = (size_t)n * 1024 + h * DK + 2 * k;
    unsigned v = *(const unsigned*)&qk[base];
    float x0 = bf2f((u16)(v & 0xffff));
    float x1 = bf2f((u16)(v >> 16));
    float2 cs = tab[s * 32 + k];
    float qs = (n < 4096) ? 0.18033688011112042f : 1.0f;   // 0.125*log2(e) for Q only
    float c = cs.x * qs, sn = cs.y * qs;
    float y0 = x0 * c - x1 * sn;
    float y1 = x1 * c + x0 * sn;
    *(unsigned*)&qk[base] = (unsigned)f2bf(y0) | ((unsigned)f2bf(y1) << 16);
}

// ---------- causal flash attention v10: mid-tile DSW (vmcnt stall hidden under QK^T) ----------
__global__ __launch_bounds__(512, 4) void attn_v10(
    const u16* __restrict__ Qp, const u16* __restrict__ Kp, const u16* __restrict__ Vt,
    u16* __restrict__ Op, float* __restrict__ mlbuf)
{
    const int slot = 39 - (int)blockIdx.x;
    const int h = blockIdx.y, b = blockIdx.z;
    int g, rr;
    if (slot < 4)       { g = 0; rr = slot; }
    else if (slot < 12) { g = 1; rr = slot - 4; }
    else if (slot < 24) { g = 2; rr = slot - 12; }
    else                { g = 3; rr = slot - 24; }
    const int qq  = rr / (g + 1);
    const int qt2 = 4 * g + qq;
    const int c   = rr - qq * (g + 1);

    const int tid  = threadIdx.x;
    const int lane = tid & 63;
    const int w    = tid >> 6;
    const int fr = lane & 15;
    const int fg = lane >> 4;
    const int bS = b * SEQ;
    const int hd = h * DK;
    const int qbase = qt2 * 128 + 16 * w;
    const int ntk = 2 * qt2 + 2;
    const int kt0 = 8 * c;
    const int kt1 = min(8 * c + 8, ntk);

    __shared__ __align__(16) u16 Kl[2][64 * 64];
    __shared__ __align__(16) u16 Vl[2][64 * 64];
    __shared__ __align__(16) u16 Plds[8][16][72];

    const int dsrow  = 8 * w + (lane >> 3);
    const int lincol = (lane & 7) * 8;
    const int dsoff  = dsrow * 64 + (((lane & 7) ^ (lane >> 3)) * 8);
    const int swz    = (fr & 7) * 8;

    const u16* qrow = Qp + (size_t)(bS + qbase + fr) * 1024 + hd;
    bf16x8 qf0 = *(const bf16x8*)(qrow + fg * 8);
    bf16x8 qf1 = *(const bf16x8*)(qrow + 32 + fg * 8);

    f32x4 o[4];
#pragma unroll
    for (int j = 0; j < 4; ++j) o[j] = (f32x4){0.f, 0.f, 0.f, 0.f};
    float mrow = -1e30f, lrow = 0.f;

    uint4 kreg, vreg;
#define LOADR(KT) do { \
    kreg = *(const uint4*)(Kp + (size_t)(bS + (KT) * 64 + dsrow) * 1024 + hd + lincol); \
    vreg = *(const uint4*)(Vt + (size_t)(hd + dsrow) * NROWS + bS + (KT) * 64 + lincol); \
} while (0)
#define DSW(BUF) do { \
    *(uint4*)&Kl[BUF][dsoff] = kreg; \
    *(uint4*)&Vl[BUF][dsoff] = vreg; \
} while (0)

    LOADR(kt0);
    DSW(0);
    if (kt0 + 1 < kt1) LOADR(kt0 + 1);
    __syncthreads();

    int cur = 0;
    for (int kt = kt0; kt < kt1; ++kt) {
        const int k0 = kt * 64;
        const bool part = (k0 <= qbase + 15);
        f32x4 sc4[4];
        if (part) {
            bf16x8 kf[4][2];
#pragma unroll
            for (int t = 0; t < 4; ++t) {
                const u16* kr = &Kl[cur][(16 * t + fr) * 64];
                kf[t][0] = *(const bf16x8*)(kr + ((fg * 8) ^ swz));
                kf[t][1] = *(const bf16x8*)(kr + (((4 + fg) * 8) ^ swz));
            }
            __builtin_amdgcn_s_setprio(1);
#pragma unroll
            for (int t = 0; t < 4; ++t) {
                f32x4 a = (f32x4){0.f, 0.f, 0.f, 0.f};
                a = __builtin_amdgcn_mfma_f32_16x16x32_bf16(kf[t][0], qf0, a, 0, 0, 0);
                a = __builtin_amdgcn_mfma_f32_16x16x32_bf16(kf[t][1], qf1, a, 0, 0, 0);
                sc4[t] = a;
            }
            __builtin_amdgcn_s_setprio(0);
            if (k0 + 63 > qbase) {       // diagonal tile: mask in place
#pragma unroll
                for (int t = 0; t < 4; ++t)
#pragma unroll
                    for (int r = 0; r < 4; ++r)
                        if (k0 + 16 * t + 4 * fg + r > qbase + fr) sc4[t][r] = -1e30f;
            }
        }
        // mid-tile staging: vmcnt wait lands after QK^T; ds_writes overlap softmax VALU
        if (kt + 1 < kt1) {
            DSW(cur ^ 1);
            if (kt + 2 < kt1) LOADR(kt + 2);
        }
        if (part) {
            // common path: direct exp2 against running max, overflow-checked
            float p[4][4];
            float rs = 0.f;
#pragma unroll
            for (int t = 0; t < 4; ++t)
#pragma unroll
                for (int r = 0; r < 4; ++r) {
                    float pv = exp2f(sc4[t][r] - mrow);
                    p[t][r] = pv;
                    rs += pv;
                }
            rs += __shfl_xor(rs, 16);
            rs += __shfl_xor(rs, 32);
            float scf = 1.0f;
            if (!__all(rs < 9.2e18f)) {
                // rare path: first tile or max grew > ~63 log2-units
                float a0 = fmaxf(fmaxf(sc4[0][0], sc4[0][1]), fmaxf(sc4[0][2], sc4[0][3]));
                float a1 = fmaxf(fmaxf(sc4[1][0], sc4[1][1]), fmaxf(sc4[1][2], sc4[1][3]));
                float a2 = fmaxf(fmaxf(sc4[2][0], sc4[2][1]), fmaxf(sc4[2][2], sc4[2][3]));
                float a3 = fmaxf(fmaxf(sc4[3][0], sc4[3][1]), fmaxf(sc4[3][2], sc4[3][3]));
                float mx = fmaxf(fmaxf(a0, a1), fmaxf(a2, a3));
                mx = fmaxf(mx, __shfl_xor(mx, 16));
                mx = fmaxf(mx, __shfl_xor(mx, 32));
                float mnew = fmaxf(mrow, mx);
                scf = exp2f(mrow - mnew);
                float s0 = __shfl(scf, 4 * fg);
                float s1 = __shfl(scf, 4 * fg + 1);
                float s2 = __shfl(scf, 4 * fg + 2);
                float s3 = __shfl(scf, 4 * fg + 3);
#pragma unroll
                for (int j = 0; j < 4; ++j) {
                    o[j][0] *= s0; o[j][1] *= s1; o[j][2] *= s2; o[j][3] *= s3;
                }
                mrow = mnew;
                rs = 0.f;
#pragma unroll
                for (int t = 0; t < 4; ++t)
#pragma unroll
                    for (int r = 0; r < 4; ++r) {
                        float pv = exp2f(sc4[t][r] - mrow);
                        p[t][r] = pv;
                        rs += pv;
                    }
                rs += __shfl_xor(rs, 16);
                rs += __shfl_xor(rs, 32);
            }
            lrow = lrow * scf + rs;
#pragma unroll
            for (int t = 0; t < 4; ++t) {
                uint2 pk;
                pk.x = cvtpk_bf16(p[t][0], p[t][1]);
                pk.y = cvtpk_bf16(p[t][2], p[t][3]);
                *(uint2*)&Plds[w][fr][16 * t + 4 * fg] = pk;
            }
            bf16x8 pf0 = *(const bf16x8*)&Plds[w][fr][fg * 8];
            bf16x8 pf1 = *(const bf16x8*)&Plds[w][fr][32 + fg * 8];
            __builtin_amdgcn_s_setprio(1);
#pragma unroll
            for (int j = 0; j < 4; ++j) {
                const u16* vr = &Vl[cur][(16 * j + fr) * 64];
                bf16x8 v0 = *(const bf16x8*)(vr + ((fg * 8) ^ swz));
                bf16x8 v1 = *(const bf16x8*)(vr + (((4 + fg) * 8) ^ swz));
                o[j] = __builtin_amdgcn_mfma_f32_16x16x32_bf16(pf0, v0, o[j], 0, 0, 0);
                o[j] = __builtin_amdgcn_mfma_f32_16x16x32_bf16(pf1, v1, o[j], 0, 0, 0);
            }
            __builtin_amdgcn_s_setprio(0);
        }
        __syncthreads();
        cur ^= 1;
    }
#undef LOADR
#undef DSW

    const int slotg = (b * NHEADS + h) * 40 + slot;
#pragma unroll
    for (int r = 0; r < 4; ++r) {
        int rrel = 16 * w + 4 * fg + r;
#pragma unroll
        for (int j = 0; j < 4; ++j)
            Op[((size_t)slotg * 128 + rrel) * 64 + 16 * j + fr] = f2bf(o[j][r]);
    }
    if (fg == 0) {
        float* pp = mlbuf + ((size_t)slotg * 128 + 16 * w + fr) * 2;
        pp[0] = mrow;
        pp[1] = lrow;
    }
}

// ---------- combine up-to-4 split-K partials -> Mb (log2-domain weights) ----------
__global__ void attn_combine3(const u16* __restrict__ Op, const float* __restrict__ mlbuf,
                              u16* __restrict__ Mb) {
    int i = blockIdx.x * blockDim.x + threadIdx.x;
    int row = i >> 7;
    int c8  = (i & 127) * 8;
    int h   = c8 >> 6;
    int s   = row & 2047;
    int b   = row >> 11;
    int qt2 = s >> 7;
    int g   = qt2 >> 2;
    int nch = g + 1;
    int slot0 = (b * NHEADS + h) * 40 + 2 * g * (g + 1) + (qt2 & 3) * (g + 1);
    int rrel = s & 127, crel = c8 & 63;

    float mv[4], lv[4];
    float m = -1e30f;
    for (int k = 0; k < nch; ++k) {
        const float* pp = mlbuf + ((size_t)(slot0 + k) * 128 + rrel) * 2;
        mv[k] = pp[0]; lv[k] = pp[1];
        m = fmaxf(m, mv[k]);
    }
    float L = 0.f;
    for (int k = 0; k < nch; ++k) {
        mv[k] = exp2f(mv[k] - m);
        L += lv[k] * mv[k];
    }
    float acc[8];
#pragma unroll
    for (int jj = 0; jj < 8; ++jj) acc[jj] = 0.f;
    for (int k = 0; k < nch; ++k) {
        float wgt = mv[k];
        uint4 u = *(const uint4*)(Op + ((size_t)(slot0 + k) * 128 + rrel) * 64 + crel);
        const unsigned* wrd = (const unsigned*)&u;
#pragma unroll
        for (int kk = 0; kk < 4; ++kk) {
            acc[2 * kk]     += wgt * bf2f((u16)(wrd[kk] & 0xffff));
            acc[2 * kk + 1] += wgt * bf2f((u16)(wrd[kk] >> 16));
        }
    }
    float inv = 1.0f / L;
    unsigned ou[4];
#pragma unroll
    for (int kk = 0; kk < 4; ++kk)
        ou[kk] = (unsigned)f2bf(acc[2 * kk] * inv) | ((unsigned)f2bf(acc[2 * kk + 1] * inv) << 16);
    *(uint4*)(Mb + (size_t)row * 1024 + c8) = *(uint4*)ou;
}

extern "C" void kernel_launch(void* const* d_in, const int* in_sizes, int n_in,
                              void* d_out, int out_size, void* d_ws, size_t ws_size,
                              hipStream_t stream) {
    const float* x   = (const float*)d_in[0];
    const int*   pos = (const int*)d_in[1];
    const float* wq  = (const float*)d_in[2];
    const float* wk  = (const float*)d_in[3];
    const float* wv  = (const float*)d_in[4];
    const float* wo  = (const float*)d_in[5];
    float* out = (float*)d_out;

    char* ws = (char*)d_ws;
    u16* xb  = (u16*)(ws);                    //  8 MB plain [4096][1024]; dead after QKV
    u16* wb  = (u16*)(ws + (24ull << 20));    //  8 MB: wq|wk|wv|wo plain, 2 MB each
    u16* wob = wb + 3 * (1 << 20);            //  [30,32) — survives to the end
    u16* Qp  = (u16*)(ws + (32ull << 20));    //  8 MB plain [4096][1024]
    u16* Kp  = (u16*)(ws + (40ull << 20));    //  8 MB plain
    u16* Vt  = (u16*)(ws + (48ull << 20));    //  8 MB plain transposed [1024][4096]
    u16* Mb  = (u16*)(ws + (56ull << 20));    //  8 MB plain [4096][1024]
    u16* Op  = (u16*)(ws);                    // 21 MB partials (reuses dead xb + gap)
    float* mlbuf = (float*)(ws + (21ull << 20));  // 1.3 MB [21, 22.3)
    float2* tab  = (float2*)(ws + (23ull << 20)); // 512 KB [23, 23.5) — RoPE table

    // 1) convert x + 4 weights to bf16 AND fill RoPE cos/sin table (one launch)
    cvt_bf16_all<<<8448, 256, 0, stream>>>(x, wq, wk, wv, wo, xb, wb, tab, pos);

    // 2) merged QKV projection (BK=64, swizzle; V via LDS relayout, Q/K direct)
    gemm_qkv_p<<<dim3(NROWS / 128, 24), 256, 0, stream>>>(xb, wb, Qp, Kp, Vt);

    // 3) RoPE in place via table (Q exp2-prescaled)
    rope_table<<<16384, 256, 0, stream>>>(Qp, tab);

    // 4) causal flash attention v10 (mid-tile DSW) + combine
    attn_v10<<<dim3(40, NHEADS, BATCH), 512, 0, stream>>>(Qp, Kp, Vt, Op, mlbuf);
    attn_combine3<<<2048, 256, 0, stream>>>(Op, mlbuf, Mb);

    // 5) output projection (BK=64, swizzled staging, f32 out)
    gemm_out_p<<<dim3(NROWS / 128, 8), 256, 0, stream>>>(Mb, wob, out);
}